// Round 4
// baseline (567.888 us; speedup 1.0000x reference)
//
#include <hip/hip_runtime.h>

#define HDIM 64
#define EPSBN 1e-5f

// ---------------- degree count / dinv ----------------
__global__ void count_edges_k(const int* __restrict__ col, int* __restrict__ cnt, int E) {
    int e = blockIdx.x * blockDim.x + threadIdx.x;
    if (e < E) atomicAdd(&cnt[col[e]], 1);
}

__global__ void dinv_k(const int* __restrict__ cnt, float* __restrict__ dinv, int n) {
    int i = blockIdx.x * blockDim.x + threadIdx.x;
    if (i < n) dinv[i] = rsqrtf((float)cnt[i] + 1.0f);   // +1 for self-loop
}

// ---------------- exclusive scan of cnt -> offs (3-phase) ----------------
__global__ void scan_partial_k(const int* __restrict__ cnt, int* __restrict__ offs,
                               int* __restrict__ bsum, int n) {
    __shared__ int lds[256];
    int tid = threadIdx.x;
    int base = blockIdx.x * 1024 + tid * 4;
    int v0 = (base + 0 < n) ? cnt[base + 0] : 0;
    int v1 = (base + 1 < n) ? cnt[base + 1] : 0;
    int v2 = (base + 2 < n) ? cnt[base + 2] : 0;
    int v3 = (base + 3 < n) ? cnt[base + 3] : 0;
    int tsum = v0 + v1 + v2 + v3;
    lds[tid] = tsum;
    __syncthreads();
    for (int off = 1; off < 256; off <<= 1) {
        int t = (tid >= off) ? lds[tid - off] : 0;
        __syncthreads();
        lds[tid] += t;
        __syncthreads();
    }
    int excl = lds[tid] - tsum;
    if (tid == 255) bsum[blockIdx.x] = lds[255];
    int run = excl;
    if (base + 0 < n) { offs[base + 0] = run; } run += v0;
    if (base + 1 < n) { offs[base + 1] = run; } run += v1;
    if (base + 2 < n) { offs[base + 2] = run; } run += v2;
    if (base + 3 < n) { offs[base + 3] = run; }
}

__global__ void scan_roots_k(int* __restrict__ bsum, int nb) {
    __shared__ int lds[256];
    int tid = threadIdx.x;
    int v = (tid < nb) ? bsum[tid] : 0;
    lds[tid] = v;
    __syncthreads();
    for (int off = 1; off < 256; off <<= 1) {
        int t = (tid >= off) ? lds[tid - off] : 0;
        __syncthreads();
        lds[tid] += t;
        __syncthreads();
    }
    if (tid < nb) bsum[tid] = lds[tid] - v;   // exclusive
}

__global__ void scan_add_k(int* __restrict__ offs, const int* __restrict__ bsum,
                           int* __restrict__ cursor, int n, int Etot) {
    int i = blockIdx.x * blockDim.x + threadIdx.x;
    if (i < n) {
        int o = offs[i] + bsum[i >> 10];
        offs[i] = o;
        cursor[i] = o;
    }
    if (i == 0) offs[n] = Etot;
}

// ---------------- CSR fill, XCD-ownership (kills 8x write amplification) ----------------
__global__ void fill_csr_k(const int* __restrict__ row, const int* __restrict__ col,
                           const float* __restrict__ dinv, int* __restrict__ cursor,
                           int2* __restrict__ srcw, int E, int N) {
    int xcd = blockIdx.x & 7;
    int chunk = blockIdx.x >> 3;
    int e = chunk * 256 + threadIdx.x;
    if (e >= E) return;
    int c = col[e];
    int owner = (int)(((unsigned long long)c * 8ull) / (unsigned)N);
    if (owner != xcd) return;
    int r = row[e];
    float w = dinv[r] * dinv[c];
    int pos = atomicAdd(&cursor[c], 1);
    srcw[pos] = make_int2(r, __float_as_int(w));
}

// ---------------- pad x [N][26] -> xp [N][32] (zeros beyond 26) ----------------
__global__ void pad_x_k(const float* __restrict__ x, float* __restrict__ xp,
                        int N, int INR) {
    int idx = blockIdx.x * blockDim.x + threadIdx.x;
    if (idx >= N * 32) return;
    int i = idx >> 5, k = idx & 31;
    xp[idx] = (k < INR) ? x[i * INR + k] : 0.f;
}

// ---------------- fused conv: wide-gather aggregate + dense + BN + ReLU ----------------
// block = 256 (4 independent waves), wave handles 4 nodes.
// Gather: LPE = KIN/4 lanes cooperate on one edge via float4 -> EPI = 64/LPE edges
// per VMEM instruction; x2 group unroll -> 2 KB in flight per wave.
// Slot reduction: shfl_xor butterfly (all lanes end with agg quad for their p).
// Dense: register-only broadcast via __shfl from lane k4 (which holds quad k4).
// No LDS, no barriers -> race-free by construction.
template <int KIN>
__global__ __launch_bounds__(256, 4) void conv_k(
    const float* __restrict__ hin, const int* __restrict__ offs,
    const int2* __restrict__ srcw, const float* __restrict__ dinv,
    const float* __restrict__ W, int KINR,
    const float* __restrict__ bias, const float* __restrict__ g,
    const float* __restrict__ bb, const float* __restrict__ m,
    const float* __restrict__ v, float* __restrict__ hout, int n) {
    constexpr int LPE = KIN / 4;     // lanes per edge
    constexpr int EPI = 64 / LPE;    // edges per gather instruction
    const int tid = threadIdx.x;
    const int wv = tid >> 6;
    const int lane = tid & 63;
    const int s = lane / LPE;        // edge slot within group
    const int p = lane % LPE;        // feature quad

    float wreg[KIN];
#pragma unroll
    for (int k = 0; k < KIN; k++) wreg[k] = (k < KINR) ? W[k * HDIM + lane] : 0.f;
    const float sc = g[lane] * rsqrtf(v[lane] + EPSBN);
    const float sh = (bias[lane] - m[lane]) * sc + bb[lane];

    const int base = blockIdx.x * 16 + wv * 4;
    for (int j = 0; j < 4; j++) {
        const int i = base + j;
        if (i >= n) break;           // wave-uniform
        const int e0 = offs[i], e1 = offs[i + 1];
        float ax = 0.f, ay = 0.f, az = 0.f, aw = 0.f;
        for (int e = e0; e < e1; e += 2 * EPI) {
            int ea = e + s, eb = e + EPI + s;
            int2 swa = make_int2(0, 0), swb = make_int2(0, 0);
            if (ea < e1) swa = srcw[ea];
            if (eb < e1) swb = srcw[eb];
            const float4 ha = *(const float4*)(hin + (size_t)swa.x * KIN + 4 * p);
            const float4 hb = *(const float4*)(hin + (size_t)swb.x * KIN + 4 * p);
            const float wa = __int_as_float(swa.y), wb = __int_as_float(swb.y);
            ax = fmaf(wa, ha.x, ax); ay = fmaf(wa, ha.y, ay);
            az = fmaf(wa, ha.z, az); aw = fmaf(wa, ha.w, aw);
            ax = fmaf(wb, hb.x, ax); ay = fmaf(wb, hb.y, ay);
            az = fmaf(wb, hb.z, az); aw = fmaf(wb, hb.w, aw);
        }
#pragma unroll
        for (int off = LPE; off < 64; off <<= 1) {
            ax += __shfl_xor(ax, off);
            ay += __shfl_xor(ay, off);
            az += __shfl_xor(az, off);
            aw += __shfl_xor(aw, off);
        }
        // self-loop, added on all lanes (value depends only on p -> consistent)
        const float di = dinv[i];
        const float dsq = di * di;
        const float4 hs = *(const float4*)(hin + (size_t)i * KIN + 4 * p);
        ax = fmaf(dsq, hs.x, ax); ay = fmaf(dsq, hs.y, ay);
        az = fmaf(dsq, hs.z, az); aw = fmaf(dsq, hs.w, aw);

        // dense: lane k4 (s=0, p=k4) holds agg quad k4; broadcast via shfl
        float dot = 0.f;
#pragma unroll
        for (int k4 = 0; k4 < KIN / 4; k4++) {
            float a0 = __shfl(ax, k4);
            float a1 = __shfl(ay, k4);
            float a2 = __shfl(az, k4);
            float a3 = __shfl(aw, k4);
            dot = fmaf(a0, wreg[4 * k4 + 0], dot);
            dot = fmaf(a1, wreg[4 * k4 + 1], dot);
            dot = fmaf(a2, wreg[4 * k4 + 2], dot);
            dot = fmaf(a3, wreg[4 * k4 + 3], dot);
        }
        hout[(size_t)i * HDIM + lane] = fmaxf(fmaf(dot, sc, sh), 0.f);
    }
}

// ---------------- pooling (4 waves per graph) + 2-layer MLP ----------------
__global__ __launch_bounds__(256) void pool_mlp_k(
    const float* __restrict__ h, const int* __restrict__ batch,
    const float* __restrict__ Wc1, const float* __restrict__ bc1,
    const float* __restrict__ Wc2, const float* __restrict__ bc2,
    float* __restrict__ out, int n) {
    int gidx = blockIdx.x;
    int tid = threadIdx.x;
    int lane = tid & 63;
    int wv = tid >> 6;

    int lo = 0, hi = n;
    while (lo < hi) { int mid = (lo + hi) >> 1; if (batch[mid] < gidx) lo = mid + 1; else hi = mid; }
    int start = lo;
    lo = start; hi = n;
    while (lo < hi) { int mid = (lo + hi) >> 1; if (batch[mid] <= gidx) lo = mid + 1; else hi = mid; }
    int end = lo;

    float sum = 0.f, mx = 0.f;   // h >= 0 post-ReLU
    for (int i = start + wv; i < end; i += 4) {
        float val = h[(size_t)i * HDIM + lane];
        sum += val;
        mx = fmaxf(mx, val);
    }
    __shared__ float ssum[4 * HDIM];
    __shared__ float smax[4 * HDIM];
    __shared__ float pooled[2 * HDIM];
    ssum[wv * HDIM + lane] = sum;
    smax[wv * HDIM + lane] = mx;
    __syncthreads();
    if (wv == 0) {
        float sv = ssum[lane] + ssum[64 + lane] + ssum[128 + lane] + ssum[192 + lane];
        float mm = fmaxf(fmaxf(smax[lane], smax[64 + lane]),
                         fmaxf(smax[128 + lane], smax[192 + lane]));
        int cnt = end - start;
        pooled[lane] = sv / fmaxf((float)cnt, 1.f);
        pooled[HDIM + lane] = mm;
    }
    __syncthreads();
    if (wv == 0) {
        float a = bc1[lane];
#pragma unroll
        for (int k = 0; k < 2 * HDIM; k++) a = fmaf(pooled[k], Wc1[k * HDIM + lane], a);
        a = fmaxf(a, 0.f);
#pragma unroll
        for (int c = 0; c < 2; c++) {
            float vv = a * Wc2[lane * 2 + c];
            for (int off = 32; off; off >>= 1) vv += __shfl_down(vv, off);
            if (lane == 0) out[gidx * 2 + c] = vv + bc2[c];
        }
    }
}

extern "C" void kernel_launch(void* const* d_in, const int* in_sizes, int n_in,
                              void* d_out, int out_size, void* d_ws, size_t ws_size,
                              hipStream_t stream) {
    const float* x    = (const float*)d_in[0];
    const int*   erow = (const int*)d_in[1];
    const int*   ecol = (const int*)d_in[2];
    const int*   batch= (const int*)d_in[3];
    const float* W0   = (const float*)d_in[4];
    const float* b0   = (const float*)d_in[5];
    const float* W1   = (const float*)d_in[6];
    const float* b1   = (const float*)d_in[7];
    const float* W2   = (const float*)d_in[8];
    const float* b2   = (const float*)d_in[9];
    const float* bn_g = (const float*)d_in[10];
    const float* bn_b = (const float*)d_in[11];
    const float* bn_m = (const float*)d_in[12];
    const float* bn_v = (const float*)d_in[13];
    const float* Wc1  = (const float*)d_in[14];
    const float* bc1  = (const float*)d_in[15];
    const float* Wc2  = (const float*)d_in[16];
    const float* bc2  = (const float*)d_in[17];
    float* out = (float*)d_out;

    const int N = in_sizes[3];
    const int E = in_sizes[1];
    const int G = out_size / 2;
    const int INR = in_sizes[0] / N;    // 26

    char* ws = (char*)d_ws;
    size_t off = 0;
    auto alloc = [&](size_t bytes) -> void* {
        void* p = ws + off;
        off += (bytes + 255) & ~(size_t)255;
        return p;
    };
    int*   cnt    = (int*)alloc((size_t)N * 4);
    float* dinv   = (float*)alloc((size_t)N * 4);
    int*   offs   = (int*)alloc((size_t)(N + 1) * 4);
    int*   cursor = (int*)alloc((size_t)N * 4);
    int*   bsum   = (int*)alloc(1024);
    int2*  srcw   = (int2*)alloc((size_t)E * 8);
    float* bufA   = (float*)alloc((size_t)N * HDIM * 4);
    float* bufB   = (float*)alloc((size_t)N * HDIM * 4);  // doubles as xp [N][32]
    (void)ws_size;

    // ---- build gcn_norm + CSR transpose ----
    hipMemsetAsync(cnt, 0, (size_t)N * 4, stream);
    count_edges_k<<<(E + 255) / 256, 256, 0, stream>>>(ecol, cnt, E);
    dinv_k<<<(N + 255) / 256, 256, 0, stream>>>(cnt, dinv, N);
    int nb = (N + 1023) / 1024;
    scan_partial_k<<<nb, 256, 0, stream>>>(cnt, offs, bsum, N);
    scan_roots_k<<<1, 256, 0, stream>>>(bsum, nb);
    scan_add_k<<<(N + 255) / 256, 256, 0, stream>>>(offs, bsum, cursor, N, E);
    int chunks = (E + 255) / 256;
    fill_csr_k<<<chunks * 8, 256, 0, stream>>>(erow, ecol, dinv, cursor, srcw, E, N);

    // ---- pad x into bufB [N][32] ----
    pad_x_k<<<(N * 32 + 255) / 256, 256, 0, stream>>>(x, bufB, N, INR);

    int cgrid = (N + 15) / 16;
    // ---- layer 0: KIN=32 (padded 26), bufB(xp) -> bufA ----
    conv_k<32><<<cgrid, 256, 0, stream>>>(bufB, offs, srcw, dinv, W0, INR, b0,
                                          bn_g + 0, bn_b + 0, bn_m + 0, bn_v + 0, bufA, N);
    // ---- layer 1: bufA -> bufB ----
    conv_k<64><<<cgrid, 256, 0, stream>>>(bufA, offs, srcw, dinv, W1, 64, b1,
                                          bn_g + 64, bn_b + 64, bn_m + 64, bn_v + 64, bufB, N);
    // ---- layer 2: bufB -> bufA ----
    conv_k<64><<<cgrid, 256, 0, stream>>>(bufB, offs, srcw, dinv, W2, 64, b2,
                                          bn_g + 128, bn_b + 128, bn_m + 128, bn_v + 128, bufA, N);

    // ---- pool + MLP ----
    pool_mlp_k<<<G, 256, 0, stream>>>(bufA, batch, Wc1, bc1, Wc2, bc2, out, N);
}